// Round 5
// baseline (485.724 us; speedup 1.0000x reference)
//
#include <hip/hip_runtime.h>
#include <hip/hip_bf16.h>
#include <stdint.h>

#define NB 8
#define NC 512
#define NN 4096
#define ND 64

typedef __attribute__((ext_vector_type(8))) short short8;
typedef __attribute__((ext_vector_type(4))) float f32x4;

#define LOG2E 1.44269504088896340736f

static __device__ __forceinline__ uint32_t cvt_pk_bf16(float lo, float hi) {
    uint32_t r;
    asm("v_cvt_pk_bf16_f32 %0, %1, %2" : "=v"(r) : "v"(lo), "v"(hi));
    return r;
}

// ---------------- Kernel A: fused QKV projection ----------------------------
// One block per (n-tile of 64, batch): computes ALL 640 outputs -> x read once.
// q rows (and bias) pre-scaled by LOG2E so attn softmax works in log2 domain.
// o in [0,64): q -> QT[b][n][o] bf16 | [64,128): k -> KT bf16 | [128,640): v -> V fp8
__global__ __launch_bounds__(256, 2) void qkv_proj(
    const float* __restrict__ x,
    const float* __restrict__ wq, const float* __restrict__ bq,
    const float* __restrict__ wk, const float* __restrict__ bk,
    const float* __restrict__ wv, const float* __restrict__ bv,
    unsigned short* __restrict__ QT, unsigned short* __restrict__ KT,
    unsigned char* __restrict__ V)
{
    const int nblk = blockIdx.x;   // 64 n-tiles
    const int b    = blockIdx.y;   // 8 batches
    const int t = threadIdx.x;
    const int wid = t >> 6;
    const int l = t & 63;
    const int lg = l >> 4, lr = l & 15;
    const int n0 = nblk * 64;
    const float* xb = x + (size_t)b * NC * NN;

    __shared__ unsigned short XT[2][64][72];   // X^T tile [n][c], +8 pad

    const int o_base = wid * 160;              // wave owns 160 o-rows

    // per-mt W row pointers + scale (uniform branch per mt)
    const float* wrow[10];
    float srow[10];
    #pragma unroll
    for (int mt = 0; mt < 10; ++mt) {
        const int ob = o_base + mt*16;
        const int o  = ob + lr;
        if (ob < 64)       { wrow[mt] = wq + (size_t)o*NC;        srow[mt] = LOG2E; }
        else if (ob < 128) { wrow[mt] = wk + (size_t)(o-64)*NC;   srow[mt] = 1.f; }
        else               { wrow[mt] = wv + (size_t)(o-128)*NC;  srow[mt] = 1.f; }
    }

    f32x4 acc[10][4];
    #pragma unroll
    for (int mt = 0; mt < 10; ++mt) {
        const int ob = o_base + mt*16;
        #pragma unroll
        for (int bb = 0; bb < 4; ++bb) {
            const int o = ob + lg*4 + bb;
            float bias = (ob < 64) ? bq[o]*LOG2E : (ob < 128) ? bk[o-64] : bv[o-128];
            #pragma unroll
            for (int nt = 0; nt < 4; ++nt) acc[mt][nt][bb] = bias;
        }
    }

    // X staging: 4x4 register micro-transpose, fp32 -> bf16
    const int cq = (t >> 4) << 2;   // c-quad 0..60
    const int n4 = (t & 15) << 2;   // n-quad 0..60
    float4 xs0, xs1, xs2, xs3;
    auto xload = [&](int ks) {
        const float* xr = xb + (size_t)(ks*64 + cq)*NN + n0 + n4;
        xs0 = *reinterpret_cast<const float4*>(xr);
        xs1 = *reinterpret_cast<const float4*>(xr + NN);
        xs2 = *reinterpret_cast<const float4*>(xr + 2*(size_t)NN);
        xs3 = *reinterpret_cast<const float4*>(xr + 3*(size_t)NN);
    };
    auto xwrite = [&](int buf) {
        uint2 w;
        w.x = cvt_pk_bf16(xs0.x, xs1.x); w.y = cvt_pk_bf16(xs2.x, xs3.x);
        *reinterpret_cast<uint2*>(&XT[buf][n4+0][cq]) = w;
        w.x = cvt_pk_bf16(xs0.y, xs1.y); w.y = cvt_pk_bf16(xs2.y, xs3.y);
        *reinterpret_cast<uint2*>(&XT[buf][n4+1][cq]) = w;
        w.x = cvt_pk_bf16(xs0.z, xs1.z); w.y = cvt_pk_bf16(xs2.z, xs3.z);
        *reinterpret_cast<uint2*>(&XT[buf][n4+2][cq]) = w;
        w.x = cvt_pk_bf16(xs0.w, xs1.w); w.y = cvt_pk_bf16(xs2.w, xs3.w);
        *reinterpret_cast<uint2*>(&XT[buf][n4+3][cq]) = w;
    };

    xload(0);
    xwrite(0);
    __syncthreads();

    for (int ks = 0; ks < 8; ++ks) {
        const int buf = ks & 1;
        const int c0 = ks * 64;
        if (ks < 7) xload(ks + 1);
        #pragma unroll
        for (int k2 = 0; k2 < 2; ++k2) {
            short8 bf[4];
            #pragma unroll
            for (int nt = 0; nt < 4; ++nt)
                bf[nt] = *reinterpret_cast<const short8*>(&XT[buf][nt*16 + lr][k2*32 + lg*8]);
            #pragma unroll
            for (int mt = 0; mt < 10; ++mt) {
                const float* wp = wrow[mt] + c0 + k2*32 + lg*8;
                float4 w0 = *reinterpret_cast<const float4*>(wp);
                float4 w1 = *reinterpret_cast<const float4*>(wp + 4);
                const float sc = srow[mt];
                union { uint32_t u[4]; short8 s; } af;
                af.u[0] = cvt_pk_bf16(w0.x*sc, w0.y*sc);
                af.u[1] = cvt_pk_bf16(w0.z*sc, w0.w*sc);
                af.u[2] = cvt_pk_bf16(w1.x*sc, w1.y*sc);
                af.u[3] = cvt_pk_bf16(w1.z*sc, w1.w*sc);
                #pragma unroll
                for (int nt = 0; nt < 4; ++nt)
                    acc[mt][nt] = __builtin_amdgcn_mfma_f32_16x16x32_bf16(af.s, bf[nt], acc[mt][nt], 0, 0, 0);
            }
        }
        if (ks < 7) xwrite(buf ^ 1);
        __syncthreads();
    }

    // epilogue: C row o = ob + 4lg+bb, col n = n0 + 16nt + lr
    #pragma unroll
    for (int mt = 0; mt < 10; ++mt) {
        const int ob = o_base + mt*16;
        const int ol = ob + lg*4;
        #pragma unroll
        for (int nt = 0; nt < 4; ++nt) {
            const int n = n0 + nt*16 + lr;
            if (ob < 128) {
                uint2 pk;
                pk.x = cvt_pk_bf16(acc[mt][nt][0], acc[mt][nt][1]);
                pk.y = cvt_pk_bf16(acc[mt][nt][2], acc[mt][nt][3]);
                unsigned short* dst = (ob < 64) ? (QT + ((size_t)b*NN + n)*ND + ol)
                                                : (KT + ((size_t)b*NN + n)*ND + (ol - 64));
                *reinterpret_cast<uint2*>(dst) = pk;
            } else {
                const int c = ol - 128;
                #pragma unroll
                for (int bb = 0; bb < 4; ++bb) {
                    int v8 = __builtin_amdgcn_cvt_pk_fp8_f32(acc[mt][nt][bb], 0.f, 0, false);
                    V[((size_t)b*NC + c + bb)*NN + n] = (unsigned char)(v8 & 0xff);
                }
            }
        }
    }
}

// ---------------- Kernel B: pipelined flash attention + residual ------------
// M=128 q/block, 8 waves, KVBLK=128, 1 barrier/iter. One-tile-lag pipeline:
// iter i: QK^T(i+1) MFMA -> rescale(i) -> PV(i) MFMA interleaved with
// softmax(i+1) VALU. All scores in log2 domain (LOG2E baked into q).
__global__ __launch_bounds__(512, 2) void attn(
    const unsigned short* __restrict__ QT,
    const unsigned short* __restrict__ KT,
    const unsigned char* __restrict__ V,
    const float* __restrict__ x,
    const float* __restrict__ alpha_p,
    float* __restrict__ out)
{
    const int bi = blockIdx.x;
    const int b  = bi & 7;            // batch per XCD (L2 locality)
    const int n0 = (bi >> 3) * 128;
    const int t = threadIdx.x;
    const int wid = t >> 6;
    const int l = t & 63;
    const int lg = l >> 4, lr = l & 15;

    __shared__ __align__(16) unsigned short Klds[2*128*64];   // [s][d^(8*(s&7))]
    __shared__ __align__(16) unsigned char  Plds[2*128*128];  // [m][s^(8*(m&15))]
    __shared__ __align__(16) float Fb[2][128];
    __shared__ __align__(16) int   Flg[2][8];
    __shared__ float Ll[128];

    const unsigned short* Qb = QT + ((size_t)b*NN + n0)*ND;
    const unsigned short* Kb = KT + (size_t)b*NN*ND;
    const unsigned char*  Vb = V + ((size_t)b*NC + 64*wid)*NN;

    short8 qf0 = *reinterpret_cast<const short8*>(Qb + (size_t)(16*wid + lr)*ND + lg*8);
    short8 qf1 = *reinterpret_cast<const short8*>(Qb + (size_t)(16*wid + lr)*ND + 32 + lg*8);

    const int kc0_row = t >> 3,          kc0_d = 8*(t & 7);
    const int kc1_row = (t + 512) >> 3,  kc1_d = 8*((t + 512) & 7);
    const int kc0_dst = kc0_row*64 + (kc0_d ^ (8*(kc0_row & 7)));
    const int kc1_dst = kc1_row*64 + (kc1_d ^ (8*(kc1_row & 7)));

    // stage K(0) -> buf0
    {
        short8 a = *reinterpret_cast<const short8*>(Kb + (size_t)t*8);
        short8 c = *reinterpret_cast<const short8*>(Kb + 4096 + (size_t)t*8);
        *reinterpret_cast<short8*>(&Klds[kc0_dst]) = a;
        *reinterpret_cast<short8*>(&Klds[kc1_dst]) = c;
    }

    f32x4 oacc[8][4];
    #pragma unroll
    for (int mt = 0; mt < 8; ++mt)
        #pragma unroll
        for (int ct = 0; ct < 4; ++ct)
            oacc[mt][ct] = f32x4{0.f, 0.f, 0.f, 0.f};

    float mrun = -1e30f, lrun = 0.f;

    long vf[4];
    #pragma unroll
    for (int ct = 0; ct < 4; ++ct)
        vf[ct] = *reinterpret_cast<const long*>(Vb + (size_t)(ct*16 + lr)*NN + 8*lg);

    __syncthreads();

    const int kswz = 8*(lr & 7);
    const int pswz = 8*lr;
    const int prow = (16*wid + lr) * 128;

    auto PVstep = [&](const unsigned char* pbase, int k2, int s_pref) {
        long vfn[4];
        #pragma unroll
        for (int ct = 0; ct < 4; ++ct)
            vfn[ct] = *reinterpret_cast<const long*>(
                Vb + (size_t)(ct*16 + lr)*NN + s_pref + 8*lg);
        long pf[8];
        #pragma unroll
        for (int mt = 0; mt < 8; ++mt)
            pf[mt] = *reinterpret_cast<const long*>(
                pbase + (16*mt + lr)*128 + ((k2*32 + 8*lg) ^ pswz));
        __builtin_amdgcn_s_setprio(1);
        #pragma unroll
        for (int mt = 0; mt < 8; ++mt)
            #pragma unroll
            for (int ct = 0; ct < 4; ++ct)
                oacc[mt][ct] = __builtin_amdgcn_mfma_f32_16x16x32_fp8_fp8(
                    pf[mt], vf[ct], oacc[mt][ct], 0, 0, 0);
        __builtin_amdgcn_s_setprio(0);
        #pragma unroll
        for (int ct = 0; ct < 4; ++ct) vf[ct] = vfn[ct];
    };

    // ---- prologue: QK^T(0) + softmax(0) -> P(0), buf0 ----
    {
        f32x4 sac[8];
        #pragma unroll
        for (int st8 = 0; st8 < 8; ++st8) {
            const unsigned short* kp = &Klds[(16*st8 + lr)*64];
            short8 a0 = *reinterpret_cast<const short8*>(kp + ((8*lg) ^ kswz));
            short8 a1 = *reinterpret_cast<const short8*>(kp + ((32 + 8*lg) ^ kswz));
            sac[st8] = __builtin_amdgcn_mfma_f32_16x16x32_bf16(a0, qf0, f32x4{0.f,0.f,0.f,0.f}, 0, 0, 0);
            sac[st8] = __builtin_amdgcn_mfma_f32_16x16x32_bf16(a1, qf1, sac[st8], 0, 0, 0);
        }
        short8 kr0 = *reinterpret_cast<const short8*>(Kb + (size_t)128*ND + t*8);
        short8 kr1 = *reinterpret_cast<const short8*>(Kb + (size_t)128*ND + 4096 + t*8);

        float pm[8];
        #pragma unroll
        for (int st8 = 0; st8 < 8; ++st8)
            pm[st8] = fmaxf(fmaxf(sac[st8][0], sac[st8][1]), fmaxf(sac[st8][2], sac[st8][3]));
        float mx = fmaxf(fmaxf(fmaxf(pm[0], pm[1]), fmaxf(pm[2], pm[3])),
                         fmaxf(fmaxf(pm[4], pm[5]), fmaxf(pm[6], pm[7])));
        mx = fmaxf(mx, __shfl_xor(mx, 16));
        mx = fmaxf(mx, __shfl_xor(mx, 32));
        float mnew = mx;
        float fsc = 0.f;
        if (l == 0) Flg[0][wid] = 1;
        if (lg == 0) Fb[0][16*wid + lr] = fsc;
        float colsum = 0.f;
        #pragma unroll
        for (int st8 = 0; st8 < 8; ++st8) {
            float p0 = __builtin_amdgcn_exp2f(sac[st8][0] - mnew);
            float p1 = __builtin_amdgcn_exp2f(sac[st8][1] - mnew);
            float p2 = __builtin_amdgcn_exp2f(sac[st8][2] - mnew);
            float p3 = __builtin_amdgcn_exp2f(sac[st8][3] - mnew);
            colsum += (p0 + p1) + (p2 + p3);
            int d = __builtin_amdgcn_cvt_pk_fp8_f32(p0, p1, 0, false);
            d = __builtin_amdgcn_cvt_pk_fp8_f32(p2, p3, d, true);
            *reinterpret_cast<int*>(&Plds[prow + ((16*st8 + 4*lg) ^ pswz)]) = d;
        }
        colsum += __shfl_xor(colsum, 16);
        colsum += __shfl_xor(colsum, 32);
        lrun = colsum;
        mrun = mnew;
        *reinterpret_cast<short8*>(&Klds[8192 + kc0_dst]) = kr0;
        *reinterpret_cast<short8*>(&Klds[8192 + kc1_dst]) = kr1;
    }
    __syncthreads();

    // ---- main loop: iter i does QK^T(i+1) + PV(i) || softmax(i+1) ----
    for (int i = 0; i < 31; ++i) {
        const int cur = i & 1, nxt = cur ^ 1;
        const unsigned char* pcur = Plds + cur*16384;
        unsigned char* pnxt = Plds + nxt*16384;
        const int s0 = i * 128;
        const int i2 = (i + 2 <= 31) ? (i + 2) : 31;

        // K(i+2) issue-early
        short8 kr0 = *reinterpret_cast<const short8*>(Kb + (size_t)(i2*128)*ND + t*8);
        short8 kr1 = *reinterpret_cast<const short8*>(Kb + (size_t)(i2*128)*ND + 4096 + t*8);

        // QK^T(i+1)
        f32x4 sn[8];
        {
            const unsigned short* kn = &Klds[nxt*8192];
            #pragma unroll
            for (int st8 = 0; st8 < 8; ++st8) {
                const unsigned short* kp = kn + (16*st8 + lr)*64;
                short8 a0 = *reinterpret_cast<const short8*>(kp + ((8*lg) ^ kswz));
                short8 a1 = *reinterpret_cast<const short8*>(kp + ((32 + 8*lg) ^ kswz));
                sn[st8] = __builtin_amdgcn_mfma_f32_16x16x32_bf16(a0, qf0, f32x4{0.f,0.f,0.f,0.f}, 0, 0, 0);
                sn[st8] = __builtin_amdgcn_mfma_f32_16x16x32_bf16(a1, qf1, sn[st8], 0, 0, 0);
            }
        }

        // conditional O-rescale for tile i (factors from softmax(i))
        {
            int4 f0 = *reinterpret_cast<const int4*>(&Flg[cur][0]);
            int4 f1 = *reinterpret_cast<const int4*>(&Flg[cur][4]);
            if (f0.x | f0.y | f0.z | f0.w | f1.x | f1.y | f1.z | f1.w) {
                #pragma unroll
                for (int mt = 0; mt < 8; ++mt) {
                    float4 fr = *reinterpret_cast<const float4*>(&Fb[cur][16*mt + 4*lg]);
                    #pragma unroll
                    for (int ct = 0; ct < 4; ++ct) {
                        oacc[mt][ct][0] *= fr.x;
                        oacc[mt][ct][1] *= fr.y;
                        oacc[mt][ct][2] *= fr.z;
                        oacc[mt][ct][3] *= fr.w;
                    }
                }
            }
        }

        float mnew, fsc, colsum = 0.f;

        PVstep(pcur, 0, s0 + 32);

        // softmax(i+1) head
        {
            float pm[8];
            #pragma unroll
            for (int st8 = 0; st8 < 8; ++st8)
                pm[st8] = fmaxf(fmaxf(sn[st8][0], sn[st8][1]), fmaxf(sn[st8][2], sn[st8][3]));
            float mx = fmaxf(fmaxf(fmaxf(pm[0], pm[1]), fmaxf(pm[2], pm[3])),
                             fmaxf(fmaxf(pm[4], pm[5]), fmaxf(pm[6], pm[7])));
            mx = fmaxf(mx, __shfl_xor(mx, 16));
            mx = fmaxf(mx, __shfl_xor(mx, 32));
            bool trig = mx > mrun + 7.0f;
            unsigned long long bal = __ballot(trig);
            mnew = bal ? fmaxf(mrun, mx) : mrun;
            fsc = __builtin_amdgcn_exp2f(mrun - mnew);
            if (l == 0) Flg[nxt][wid] = (bal != 0ULL);
            if (lg == 0) Fb[nxt][16*wid + lr] = fsc;
        }

        PVstep(pcur, 1, s0 + 64);

        #pragma unroll
        for (int st8 = 0; st8 < 4; ++st8) {
            float p0 = __builtin_amdgcn_exp2f(sn[st8][0] - mnew);
            float p1 = __builtin_amdgcn_exp2f(sn[st8][1] - mnew);
            float p2 = __builtin_amdgcn_exp2f(sn[st8][2] - mnew);
            float p3 = __builtin_amdgcn_exp2f(sn[st8][3] - mnew);
            colsum += (p0 + p1) + (p2 + p3);
            int d = __builtin_amdgcn_cvt_pk_fp8_f32(p0, p1, 0, false);
            d = __builtin_amdgcn_cvt_pk_fp8_f32(p2, p3, d, true);
            *reinterpret_cast<int*>(&pnxt[prow + ((16*st8 + 4*lg) ^ pswz)]) = d;
        }

        PVstep(pcur, 2, s0 + 96);

        #pragma unroll
        for (int st8 = 4; st8 < 8; ++st8) {
            float p0 = __builtin_amdgcn_exp2f(sn[st8][0] - mnew);
            float p1 = __builtin_amdgcn_exp2f(sn[st8][1] - mnew);
            float p2 = __builtin_amdgcn_exp2f(sn[st8][2] - mnew);
            float p3 = __builtin_amdgcn_exp2f(sn[st8][3] - mnew);
            colsum += (p0 + p1) + (p2 + p3);
            int d = __builtin_amdgcn_cvt_pk_fp8_f32(p0, p1, 0, false);
            d = __builtin_amdgcn_cvt_pk_fp8_f32(p2, p3, d, true);
            *reinterpret_cast<int*>(&pnxt[prow + ((16*st8 + 4*lg) ^ pswz)]) = d;
        }

        PVstep(pcur, 3, s0 + 128);

        colsum += __shfl_xor(colsum, 16);
        colsum += __shfl_xor(colsum, 32);
        lrun = lrun * fsc + colsum;
        mrun = mnew;

        *reinterpret_cast<short8*>(&Klds[cur*8192 + kc0_dst]) = kr0;
        *reinterpret_cast<short8*>(&Klds[cur*8192 + kc1_dst]) = kr1;

        __syncthreads();
    }

    // ---- tail: PV(31) ----
    {
        const unsigned char* pcur = Plds + 16384;   // 31 & 1 = 1
        const int s0 = 31 * 128;
        int4 f0 = *reinterpret_cast<const int4*>(&Flg[1][0]);
        int4 f1 = *reinterpret_cast<const int4*>(&Flg[1][4]);
        if (f0.x | f0.y | f0.z | f0.w | f1.x | f1.y | f1.z | f1.w) {
            #pragma unroll
            for (int mt = 0; mt < 8; ++mt) {
                float4 fr = *reinterpret_cast<const float4*>(&Fb[1][16*mt + 4*lg]);
                #pragma unroll
                for (int ct = 0; ct < 4; ++ct) {
                    oacc[mt][ct][0] *= fr.x;
                    oacc[mt][ct][1] *= fr.y;
                    oacc[mt][ct][2] *= fr.z;
                    oacc[mt][ct][3] *= fr.w;
                }
            }
        }
        PVstep(pcur, 0, s0 + 32);
        PVstep(pcur, 1, s0 + 64);
        PVstep(pcur, 2, s0 + 96);
        PVstep(pcur, 3, s0);       // dummy prefetch (clamped)
    }

    if (lg == 0) Ll[16*wid + lr] = lrun;
    __syncthreads();

    const float alpha = alpha_p[0];
    #pragma unroll
    for (int mt = 0; mt < 8; ++mt) {
        float4 l4 = *reinterpret_cast<const float4*>(&Ll[16*mt + 4*lg]);
        float ar0 = alpha / l4.x, ar1 = alpha / l4.y, ar2 = alpha / l4.z, ar3 = alpha / l4.w;
        #pragma unroll
        for (int ct = 0; ct < 4; ++ct) {
            const int c = 64*wid + 16*ct + lr;
            const size_t base = ((size_t)b*NC + c)*NN + n0 + 16*mt + 4*lg;
            float4 x4 = *reinterpret_cast<const float4*>(x + base);
            float4 o4;
            o4.x = oacc[mt][ct][0] * ar0 + x4.x;
            o4.y = oacc[mt][ct][1] * ar1 + x4.y;
            o4.z = oacc[mt][ct][2] * ar2 + x4.z;
            o4.w = oacc[mt][ct][3] * ar3 + x4.w;
            *reinterpret_cast<float4*>(out + base) = o4;
        }
    }
}

extern "C" void kernel_launch(void* const* d_in, const int* in_sizes, int n_in,
                              void* d_out, int out_size, void* d_ws, size_t ws_size,
                              hipStream_t stream) {
    const float* x     = (const float*)d_in[0];
    const float* wq    = (const float*)d_in[1];
    const float* bq    = (const float*)d_in[2];
    const float* wk    = (const float*)d_in[3];
    const float* bk    = (const float*)d_in[4];
    const float* wv    = (const float*)d_in[5];
    const float* bv    = (const float*)d_in[6];
    const float* alpha = (const float*)d_in[7];

    // ws: QT bf16 4MB | KT bf16 4MB | V fp8 16MB
    unsigned short* QT = (unsigned short*)d_ws;
    unsigned short* KT = QT + (size_t)NB*NN*ND;
    unsigned char*  V  = (unsigned char*)(KT + (size_t)NB*NN*ND);

    dim3 gA(64, 8);
    qkv_proj<<<gA, 256, 0, stream>>>(x, wq, bq, wk, bk, wv, bv, QT, KT, V);
    attn<<<NB * (NN/128), 512, 0, stream>>>(QT, KT, V, x, alpha, (float*)d_out);
}

// Round 6
// 221.171 us; speedup vs baseline: 2.1961x; 2.1961x over previous
//
#include <hip/hip_runtime.h>
#include <hip/hip_bf16.h>
#include <stdint.h>

#define NB 8
#define NC 512
#define NN 4096
#define ND 64

typedef __attribute__((ext_vector_type(8))) short short8;
typedef __attribute__((ext_vector_type(4))) float f32x4;

#define LOG2E 1.44269504088896340736f

static __device__ __forceinline__ uint32_t cvt_pk_bf16(float lo, float hi) {
    uint32_t r;
    asm("v_cvt_pk_bf16_f32 %0, %1, %2" : "=v"(r) : "v"(lo), "v"(hi));
    return r;
}

// ---------------- Kernel 0: W fp32 -> bf16 (LOG2E baked into q rows) --------
__global__ __launch_bounds__(256) void wprep(
    const float* __restrict__ wq, const float* __restrict__ wk,
    const float* __restrict__ wv, unsigned short* __restrict__ Wbf)
{
    const int g = blockIdx.x * 256 + threadIdx.x;   // 640*512/8 = 40960 threads
    const int o = g >> 6;
    const int c = (g & 63) << 3;
    const float* src; float sc;
    if (o < 64)       { src = wq + (size_t)o*NC;        sc = LOG2E; }
    else if (o < 128) { src = wk + (size_t)(o-64)*NC;   sc = 1.f; }
    else              { src = wv + (size_t)(o-128)*NC;  sc = 1.f; }
    float4 a = *reinterpret_cast<const float4*>(src + c);
    float4 d = *reinterpret_cast<const float4*>(src + c + 4);
    uint4 r;
    r.x = cvt_pk_bf16(a.x*sc, a.y*sc);
    r.y = cvt_pk_bf16(a.z*sc, a.w*sc);
    r.z = cvt_pk_bf16(d.x*sc, d.y*sc);
    r.w = cvt_pk_bf16(d.z*sc, d.w*sc);
    *reinterpret_cast<uint4*>(Wbf + (size_t)o*NC + c) = r;
}

// ---------------- Kernel A: fused QKV projection ----------------------------
// One block per (n-tile of 64, batch); W read as bf16 frags from L2.
__global__ __launch_bounds__(256, 2) void qkv_proj(
    const float* __restrict__ x,
    const unsigned short* __restrict__ Wbf,
    const float* __restrict__ bq, const float* __restrict__ bk,
    const float* __restrict__ bv,
    unsigned short* __restrict__ QT, unsigned short* __restrict__ KT,
    unsigned char* __restrict__ V)
{
    const int nblk = blockIdx.x;
    const int b    = blockIdx.y;
    const int t = threadIdx.x;
    const int wid = t >> 6;
    const int l = t & 63;
    const int lg = l >> 4, lr = l & 15;
    const int n0 = nblk * 64;
    const float* xb = x + (size_t)b * NC * NN;

    __shared__ unsigned short XT[2][64][72];   // X^T tile [n][c], +8 pad

    const int o_base = wid * 160;

    f32x4 acc[10][4];
    #pragma unroll
    for (int mt = 0; mt < 10; ++mt) {
        const int ob = o_base + mt*16;
        #pragma unroll
        for (int bb = 0; bb < 4; ++bb) {
            const int o = ob + lg*4 + bb;
            float bias = (ob < 64) ? bq[o]*LOG2E : (ob < 128) ? bk[o-64] : bv[o-128];
            #pragma unroll
            for (int nt = 0; nt < 4; ++nt) acc[mt][nt][bb] = bias;
        }
    }

    const int cq = (t >> 4) << 2;
    const int n4 = (t & 15) << 2;
    float4 xs0, xs1, xs2, xs3;
    auto xload = [&](int ks) {
        const float* xr = xb + (size_t)(ks*64 + cq)*NN + n0 + n4;
        xs0 = *reinterpret_cast<const float4*>(xr);
        xs1 = *reinterpret_cast<const float4*>(xr + NN);
        xs2 = *reinterpret_cast<const float4*>(xr + 2*(size_t)NN);
        xs3 = *reinterpret_cast<const float4*>(xr + 3*(size_t)NN);
    };
    auto xwrite = [&](int buf) {
        uint2 w;
        w.x = cvt_pk_bf16(xs0.x, xs1.x); w.y = cvt_pk_bf16(xs2.x, xs3.x);
        *reinterpret_cast<uint2*>(&XT[buf][n4+0][cq]) = w;
        w.x = cvt_pk_bf16(xs0.y, xs1.y); w.y = cvt_pk_bf16(xs2.y, xs3.y);
        *reinterpret_cast<uint2*>(&XT[buf][n4+1][cq]) = w;
        w.x = cvt_pk_bf16(xs0.z, xs1.z); w.y = cvt_pk_bf16(xs2.z, xs3.z);
        *reinterpret_cast<uint2*>(&XT[buf][n4+2][cq]) = w;
        w.x = cvt_pk_bf16(xs0.w, xs1.w); w.y = cvt_pk_bf16(xs2.w, xs3.w);
        *reinterpret_cast<uint2*>(&XT[buf][n4+3][cq]) = w;
    };

    xload(0);
    xwrite(0);
    __syncthreads();

    for (int ks = 0; ks < 8; ++ks) {
        const int buf = ks & 1;
        const int c0 = ks * 64;
        if (ks < 7) xload(ks + 1);
        #pragma unroll
        for (int k2 = 0; k2 < 2; ++k2) {
            short8 bf[4];
            #pragma unroll
            for (int nt = 0; nt < 4; ++nt)
                bf[nt] = *reinterpret_cast<const short8*>(&XT[buf][nt*16 + lr][k2*32 + lg*8]);
            #pragma unroll
            for (int mt = 0; mt < 10; ++mt) {
                short8 af = *reinterpret_cast<const short8*>(
                    Wbf + (size_t)(o_base + mt*16 + lr)*NC + c0 + k2*32 + lg*8);
                #pragma unroll
                for (int nt = 0; nt < 4; ++nt)
                    acc[mt][nt] = __builtin_amdgcn_mfma_f32_16x16x32_bf16(af, bf[nt], acc[mt][nt], 0, 0, 0);
            }
        }
        if (ks < 7) xwrite(buf ^ 1);
        __syncthreads();
    }

    #pragma unroll
    for (int mt = 0; mt < 10; ++mt) {
        const int ob = o_base + mt*16;
        const int ol = ob + lg*4;
        #pragma unroll
        for (int nt = 0; nt < 4; ++nt) {
            const int n = n0 + nt*16 + lr;
            if (ob < 128) {
                uint2 pk;
                pk.x = cvt_pk_bf16(acc[mt][nt][0], acc[mt][nt][1]);
                pk.y = cvt_pk_bf16(acc[mt][nt][2], acc[mt][nt][3]);
                unsigned short* dst = (ob < 64) ? (QT + ((size_t)b*NN + n)*ND + ol)
                                                : (KT + ((size_t)b*NN + n)*ND + (ol - 64));
                *reinterpret_cast<uint2*>(dst) = pk;
            } else {
                const int c = ol - 128;
                #pragma unroll
                for (int bb = 0; bb < 4; ++bb) {
                    int v8 = __builtin_amdgcn_cvt_pk_fp8_f32(acc[mt][nt][bb], 0.f, 0, false);
                    V[((size_t)b*NC + c + bb)*NN + n] = (unsigned char)(v8 & 0xff);
                }
            }
        }
    }
}

// ---------------- Kernel B: pipelined flash attention + residual ------------
// M=128 q/block, 8 waves, KVBLK=64, 1 barrier/tile. One-tile-lag pipeline with
// small state: iter i = QK^T(i+1) [8 MFMA] -> rescale(i) -> PV(i) [2x32 MFMA]
// interleaved with softmax(i+1) VALU. Scores in log2 domain.
__global__ __launch_bounds__(512, 2) void attn(
    const unsigned short* __restrict__ QT,
    const unsigned short* __restrict__ KT,
    const unsigned char* __restrict__ V,
    const float* __restrict__ x,
    const float* __restrict__ alpha_p,
    float* __restrict__ out)
{
    const int bi = blockIdx.x;
    const int b  = bi & 7;            // batch per XCD (L2 locality)
    const int n0 = (bi >> 3) * 128;
    const int t = threadIdx.x;
    const int wid = t >> 6;
    const int l = t & 63;
    const int lg = l >> 4, lr = l & 15;

    __shared__ __align__(16) unsigned short Klds[2*64*64];   // 16 KB, swizzled
    __shared__ __align__(16) unsigned char  Plds[2*128*64];  // 16 KB, swizzled
    __shared__ __align__(16) float Fb[2][128];
    __shared__ int   Flg[2][8];
    __shared__ float Ll[128];

    const unsigned short* Qb = QT + ((size_t)b*NN + n0)*ND;
    const unsigned short* Kb = KT + (size_t)b*NN*ND;
    const unsigned char*  Vb = V + ((size_t)b*NC + 64*wid)*NN;

    short8 qf0 = *reinterpret_cast<const short8*>(Qb + (size_t)(16*wid + lr)*ND + lg*8);
    short8 qf1 = *reinterpret_cast<const short8*>(Qb + (size_t)(16*wid + lr)*ND + 32 + lg*8);

    // K staging: one short8 per thread per tile (64x64 shorts)
    const int krow = t >> 3;
    const int kdst = krow*64 + ((8*(t & 7)) ^ (8*(krow & 7)));

    {   // stage K(0) -> buf0
        short8 k0 = *reinterpret_cast<const short8*>(Kb + (size_t)t*8);
        *reinterpret_cast<short8*>(&Klds[kdst]) = k0;
    }

    f32x4 oacc[8][4];
    #pragma unroll
    for (int mt = 0; mt < 8; ++mt)
        #pragma unroll
        for (int ct = 0; ct < 4; ++ct)
            oacc[mt][ct] = f32x4{0.f, 0.f, 0.f, 0.f};

    float mrun = -1e30f, lrun = 0.f;

    long vf[4];   // V frags for the upcoming PV k2-step
    #pragma unroll
    for (int ct = 0; ct < 4; ++ct)
        vf[ct] = *reinterpret_cast<const long*>(Vb + (size_t)(ct*16 + lr)*NN + 8*lg);

    __syncthreads();   // K(0) visible

    const int swz = 8*(lr & 7);
    const int prow = (16*wid + lr) * 64;

    auto PVstep = [&](const unsigned char* pbase, int k2, int s_pref) {
        long vfn[4];
        #pragma unroll
        for (int ct = 0; ct < 4; ++ct)
            vfn[ct] = *reinterpret_cast<const long*>(
                Vb + (size_t)(ct*16 + lr)*NN + s_pref + 8*lg);
        long pf[8];
        #pragma unroll
        for (int mt = 0; mt < 8; ++mt)
            pf[mt] = *reinterpret_cast<const long*>(
                pbase + (16*mt + lr)*64 + ((k2*32 + 8*lg) ^ swz));
        __builtin_amdgcn_s_setprio(1);
        #pragma unroll
        for (int mt = 0; mt < 8; ++mt)
            #pragma unroll
            for (int ct = 0; ct < 4; ++ct)
                oacc[mt][ct] = __builtin_amdgcn_mfma_f32_16x16x32_fp8_fp8(
                    pf[mt], vf[ct], oacc[mt][ct], 0, 0, 0);
        __builtin_amdgcn_s_setprio(0);
        #pragma unroll
        for (int ct = 0; ct < 4; ++ct) vf[ct] = vfn[ct];
    };

    // ---- prologue: QK^T(0) + softmax(0) -> P(0) buf0; stage K(1) -> buf1 ----
    {
        f32x4 sac[4];
        #pragma unroll
        for (int st8 = 0; st8 < 4; ++st8) {
            const unsigned short* kp = &Klds[(16*st8 + lr)*64];
            short8 a0 = *reinterpret_cast<const short8*>(kp + ((8*lg) ^ swz));
            short8 a1 = *reinterpret_cast<const short8*>(kp + ((32 + 8*lg) ^ swz));
            sac[st8] = __builtin_amdgcn_mfma_f32_16x16x32_bf16(a0, qf0, f32x4{0.f,0.f,0.f,0.f}, 0, 0, 0);
            sac[st8] = __builtin_amdgcn_mfma_f32_16x16x32_bf16(a1, qf1, sac[st8], 0, 0, 0);
        }
        short8 kr = *reinterpret_cast<const short8*>(Kb + 4096 + (size_t)t*8);  // K(1)

        float mx = fmaxf(fmaxf(sac[0][0], sac[0][1]), fmaxf(sac[0][2], sac[0][3]));
        #pragma unroll
        for (int st8 = 1; st8 < 4; ++st8)
            mx = fmaxf(mx, fmaxf(fmaxf(sac[st8][0], sac[st8][1]), fmaxf(sac[st8][2], sac[st8][3])));
        mx = fmaxf(mx, __shfl_xor(mx, 16));
        mx = fmaxf(mx, __shfl_xor(mx, 32));
        const float mnew = mx;
        if (l == 0) Flg[0][wid] = 1;
        if (lg == 0) Fb[0][16*wid + lr] = 0.f;
        float colsum = 0.f;
        #pragma unroll
        for (int st8 = 0; st8 < 4; ++st8) {
            float p0 = __builtin_amdgcn_exp2f(sac[st8][0] - mnew);
            float p1 = __builtin_amdgcn_exp2f(sac[st8][1] - mnew);
            float p2 = __builtin_amdgcn_exp2f(sac[st8][2] - mnew);
            float p3 = __builtin_amdgcn_exp2f(sac[st8][3] - mnew);
            colsum += (p0 + p1) + (p2 + p3);
            int d = __builtin_amdgcn_cvt_pk_fp8_f32(p0, p1, 0, false);
            d = __builtin_amdgcn_cvt_pk_fp8_f32(p2, p3, d, true);
            *reinterpret_cast<int*>(&Plds[prow + ((16*st8 + 4*lg) ^ swz)]) = d;
        }
        colsum += __shfl_xor(colsum, 16);
        colsum += __shfl_xor(colsum, 32);
        lrun = colsum;
        mrun = mnew;
        *reinterpret_cast<short8*>(&Klds[4096 + kdst]) = kr;
    }
    __syncthreads();   // P(0), K(1) visible

    // ---- main loop over 64-key tiles ----
    for (int i = 0; i < 63; ++i) {
        const int cur = i & 1, nxt = cur ^ 1;
        const unsigned char* pcur = Plds + cur*8192;
        unsigned char* pnxt = Plds + nxt*8192;
        const int s0 = i * 64;
        const int ipre = (i + 2 < 64) ? (i + 2) : 63;

        // K(i+2) issue-early (written to LDS at iter end)
        short8 kr = *reinterpret_cast<const short8*>(Kb + (size_t)ipre*4096 + t*8);

        // QK^T(i+1) from Kbuf[nxt]
        f32x4 sn[4];
        {
            const unsigned short* kbuf = &Klds[nxt*4096];
            #pragma unroll
            for (int st8 = 0; st8 < 4; ++st8) {
                const unsigned short* kp = kbuf + (16*st8 + lr)*64;
                short8 a0 = *reinterpret_cast<const short8*>(kp + ((8*lg) ^ swz));
                short8 a1 = *reinterpret_cast<const short8*>(kp + ((32 + 8*lg) ^ swz));
                sn[st8] = __builtin_amdgcn_mfma_f32_16x16x32_bf16(a0, qf0, f32x4{0.f,0.f,0.f,0.f}, 0, 0, 0);
                sn[st8] = __builtin_amdgcn_mfma_f32_16x16x32_bf16(a1, qf1, sn[st8], 0, 0, 0);
            }
        }

        // conditional O-rescale for tile i
        {
            int4 f0 = *reinterpret_cast<const int4*>(&Flg[cur][0]);
            int4 f1 = *reinterpret_cast<const int4*>(&Flg[cur][4]);
            if (f0.x | f0.y | f0.z | f0.w | f1.x | f1.y | f1.z | f1.w) {
                #pragma unroll
                for (int mt = 0; mt < 8; ++mt) {
                    float4 fr = *reinterpret_cast<const float4*>(&Fb[cur][16*mt + 4*lg]);
                    #pragma unroll
                    for (int ct = 0; ct < 4; ++ct) {
                        oacc[mt][ct][0] *= fr.x;
                        oacc[mt][ct][1] *= fr.y;
                        oacc[mt][ct][2] *= fr.z;
                        oacc[mt][ct][3] *= fr.w;
                    }
                }
            }
        }

        PVstep(pcur, 0, s0 + 32);          // PV(i) k2=0; prefetch V k2=1

        // softmax(i+1): max, flags, exp+pack -> pnxt   (overlaps PV MFMA)
        float mnew, fsc, colsum = 0.f;
        {
            float mx = fmaxf(fmaxf(sn[0][0], sn[0][1]), fmaxf(sn[0][2], sn[0][3]));
            #pragma unroll
            for (int st8 = 1; st8 < 4; ++st8)
                mx = fmaxf(mx, fmaxf(fmaxf(sn[st8][0], sn[st8][1]), fmaxf(sn[st8][2], sn[st8][3])));
            mx = fmaxf(mx, __shfl_xor(mx, 16));
            mx = fmaxf(mx, __shfl_xor(mx, 32));
            bool trig = mx > mrun + 7.0f;
            unsigned long long bal = __ballot(trig);
            mnew = bal ? fmaxf(mrun, mx) : mrun;
            fsc = __builtin_amdgcn_exp2f(mrun - mnew);
            if (l == 0) Flg[nxt][wid] = (bal != 0ULL);
            if (lg == 0) Fb[nxt][16*wid + lr] = fsc;
            #pragma unroll
            for (int st8 = 0; st8 < 4; ++st8) {
                float p0 = __builtin_amdgcn_exp2f(sn[st8][0] - mnew);
                float p1 = __builtin_amdgcn_exp2f(sn[st8][1] - mnew);
                float p2 = __builtin_amdgcn_exp2f(sn[st8][2] - mnew);
                float p3 = __builtin_amdgcn_exp2f(sn[st8][3] - mnew);
                colsum += (p0 + p1) + (p2 + p3);
                int d = __builtin_amdgcn_cvt_pk_fp8_f32(p0, p1, 0, false);
                d = __builtin_amdgcn_cvt_pk_fp8_f32(p2, p3, d, true);
                *reinterpret_cast<int*>(&pnxt[prow + ((16*st8 + 4*lg) ^ swz)]) = d;
            }
        }

        PVstep(pcur, 1, s0 + 64);          // PV(i) k2=1; prefetch next-tile V k2=0

        colsum += __shfl_xor(colsum, 16);
        colsum += __shfl_xor(colsum, 32);
        lrun = lrun * fsc + colsum;
        mrun = mnew;

        *reinterpret_cast<short8*>(&Klds[cur*4096 + kdst]) = kr;   // K(i+2)

        __syncthreads();
    }

    // ---- tail: PV(63) ----
    {
        const unsigned char* pcur = Plds + 8192;    // 63 & 1 = 1
        const int s0 = 63 * 64;
        int4 f0 = *reinterpret_cast<const int4*>(&Flg[1][0]);
        int4 f1 = *reinterpret_cast<const int4*>(&Flg[1][4]);
        if (f0.x | f0.y | f0.z | f0.w | f1.x | f1.y | f1.z | f1.w) {
            #pragma unroll
            for (int mt = 0; mt < 8; ++mt) {
                float4 fr = *reinterpret_cast<const float4*>(&Fb[1][16*mt + 4*lg]);
                #pragma unroll
                for (int ct = 0; ct < 4; ++ct) {
                    oacc[mt][ct][0] *= fr.x;
                    oacc[mt][ct][1] *= fr.y;
                    oacc[mt][ct][2] *= fr.z;
                    oacc[mt][ct][3] *= fr.w;
                }
            }
        }
        PVstep(pcur, 0, s0 + 32);
        PVstep(pcur, 1, s0);               // dummy prefetch
    }

    if (lg == 0) Ll[16*wid + lr] = lrun;
    __syncthreads();

    const float alpha = alpha_p[0];
    #pragma unroll
    for (int mt = 0; mt < 8; ++mt) {
        float4 l4 = *reinterpret_cast<const float4*>(&Ll[16*mt + 4*lg]);
        float ar0 = alpha / l4.x, ar1 = alpha / l4.y, ar2 = alpha / l4.z, ar3 = alpha / l4.w;
        #pragma unroll
        for (int ct = 0; ct < 4; ++ct) {
            const int c = 64*wid + 16*ct + lr;
            const size_t base = ((size_t)b*NC + c)*NN + n0 + 16*mt + 4*lg;
            float4 x4 = *reinterpret_cast<const float4*>(x + base);
            float4 o4;
            o4.x = oacc[mt][ct][0] * ar0 + x4.x;
            o4.y = oacc[mt][ct][1] * ar1 + x4.y;
            o4.z = oacc[mt][ct][2] * ar2 + x4.z;
            o4.w = oacc[mt][ct][3] * ar3 + x4.w;
            *reinterpret_cast<float4*>(out + base) = o4;
        }
    }
}

extern "C" void kernel_launch(void* const* d_in, const int* in_sizes, int n_in,
                              void* d_out, int out_size, void* d_ws, size_t ws_size,
                              hipStream_t stream) {
    const float* x     = (const float*)d_in[0];
    const float* wq    = (const float*)d_in[1];
    const float* bq    = (const float*)d_in[2];
    const float* wk    = (const float*)d_in[3];
    const float* bk    = (const float*)d_in[4];
    const float* wv    = (const float*)d_in[5];
    const float* bv    = (const float*)d_in[6];
    const float* alpha = (const float*)d_in[7];

    // ws: QT bf16 4MB | KT bf16 4MB | V fp8 16MB | Wbf bf16 640KB
    unsigned short* QT = (unsigned short*)d_ws;
    unsigned short* KT = QT + (size_t)NB*NN*ND;
    unsigned char*  V  = (unsigned char*)(KT + (size_t)NB*NN*ND);
    unsigned short* Wbf = (unsigned short*)(V + (size_t)NB*NC*NN);

    wprep<<<160, 256, 0, stream>>>(wq, wk, wv, Wbf);
    dim3 gA(64, 8);
    qkv_proj<<<gA, 256, 0, stream>>>(x, Wbf, bq, bk, bv, QT, KT, V);
    attn<<<NB * (NN/128), 512, 0, stream>>>(QT, KT, V, x, alpha, (float*)d_out);
}